// Round 1
// baseline (1737.574 us; speedup 1.0000x reference)
//
#include <hip/hip_runtime.h>
#include <stdint.h>

#define HID 2048
#define SEQ 4096
#define NVOCAB 32000
#define CHUNK 64
#define NCHUNK 64

typedef _Float16 f16;
typedef _Float16 f16x4 __attribute__((ext_vector_type(4)));
typedef _Float16 f16x8 __attribute__((ext_vector_type(8)));
typedef float f32x4 __attribute__((ext_vector_type(4)));

constexpr float ENC_SCALE   = 16.0f;                 // 2 identity MoE layers, 4^2
constexpr float CPT_SCALE   = 70368744177664.0f;     // 4^23 = 2^46 (exact in fp32)
constexpr float SPLIT_SCALE = 1024.0f;               // pre-scale before fp16 split (cos scale-invariant)
constexpr float LM_SCALE    = 1024.0f;               // lm_w -> fp16 scale
constexpr float OUT_SCALE   = 0x1p-36f;              // DEC_SCALE(16) * 2^-40 : keeps h_out in fp16 range
constexpr float FINAL_SCALE = 0x1p30f;               // undo 2^-40 (h) * 2^10 (lm_w)

// ---- async global->LDS, 16B per lane. LDS dest must be wave-uniform base + lane*16. ----
__device__ __forceinline__ void async_copy16(const void* g, void* l) {
  __builtin_amdgcn_global_load_lds(
      (const __attribute__((address_space(1))) void*)(uintptr_t)g,
      (__attribute__((address_space(3))) void*)(uint32_t)(uintptr_t)l,
      16, 0, 0);
}

// ---------------- gather + fp16 hi/lo split of h ----------------
__global__ void gather_split(const int* __restrict__ ids, const float* __restrict__ emb,
                             float* __restrict__ h, f16* __restrict__ hhi, f16* __restrict__ hlo) {
  int t = blockIdx.x;
  size_t base = (size_t)ids[t] * HID;
  size_t ob   = (size_t)t * HID;
  #pragma unroll
  for (int s = 0; s < 2; ++s) {
    int j = s * 1024 + threadIdx.x * 4;
    float4 v = *(const float4*)(emb + base + j);
    v.x *= ENC_SCALE; v.y *= ENC_SCALE; v.z *= ENC_SCALE; v.w *= ENC_SCALE;
    *(float4*)(h + ob + j) = v;
    float sx = v.x * SPLIT_SCALE, sy = v.y * SPLIT_SCALE, sz = v.z * SPLIT_SCALE, sw = v.w * SPLIT_SCALE;
    f16x4 hi, lo;
    hi.x = (f16)sx; lo.x = (f16)(sx - (float)hi.x);
    hi.y = (f16)sy; lo.y = (f16)(sy - (float)hi.y);
    hi.z = (f16)sz; lo.z = (f16)(sz - (float)hi.z);
    hi.w = (f16)sw; lo.w = (f16)(sw - (float)hi.w);
    *(f16x4*)(hhi + ob + j) = hi;
    *(f16x4*)(hlo + ob + j) = lo;
  }
}

// ---------------- fp16 hi/lo split of a weight matrix (2048x2048) ----------------
__global__ void split_w(const float* __restrict__ w, f16* __restrict__ whi, f16* __restrict__ wlo) {
  size_t i = ((size_t)blockIdx.x * 256 + threadIdx.x) * 4;
  float4 v = *(const float4*)(w + i);
  float sx = v.x * SPLIT_SCALE, sy = v.y * SPLIT_SCALE, sz = v.z * SPLIT_SCALE, sw = v.w * SPLIT_SCALE;
  f16x4 hi, lo;
  hi.x = (f16)sx; lo.x = (f16)(sx - (float)hi.x);
  hi.y = (f16)sy; lo.y = (f16)(sy - (float)hi.y);
  hi.z = (f16)sz; lo.z = (f16)(sz - (float)hi.z);
  hi.w = (f16)sw; lo.w = (f16)(sw - (float)hi.w);
  *(f16x4*)(whi + i) = hi;
  *(f16x4*)(wlo + i) = lo;
}

// ---------------- lm_w -> fp16 (x1024) ----------------
__global__ void conv_lm(const float* __restrict__ w, f16* __restrict__ o) {
  size_t i = ((size_t)blockIdx.x * 256 + threadIdx.x) * 4;
  float4 v = *(const float4*)(w + i);
  f16x4 r;
  r.x = (f16)(v.x * LM_SCALE); r.y = (f16)(v.y * LM_SCALE);
  r.z = (f16)(v.z * LM_SCALE); r.w = (f16)(v.w * LM_SCALE);
  *(f16x4*)(o + i) = r;
}

// ---------------- split-fp16 GEMM: C[M,N] = A[M,K] * B[N,K]^T (3-product hi/lo) ----------------
// M=4096, K=2048, B has N rows (qw stacked on kw -> N=4096). ~fp32 accuracy for cos_sim.
__global__ __launch_bounds__(256) void gemm_split3(
    const f16* __restrict__ Ah, const f16* __restrict__ Al,
    const f16* __restrict__ Bh, const f16* __restrict__ Bl,
    float* __restrict__ C, int ldc) {
  __shared__ __align__(16) f16 sAh[128 * 32], sAl[128 * 32], sBh[128 * 32], sBl[128 * 32];
  const int m0 = blockIdx.x * 128, n0 = blockIdx.y * 128;
  const int t = threadIdx.x;
  const int lane = t & 63, wave = t >> 6;
  const int wm = (wave >> 1) * 64, wn = (wave & 1) * 64;
  const int srow = t >> 2, scol = (t & 3) * 8;      // staging: 16B per lane, 4 lanes/row
  const int lm = lane & 15, lk = (lane >> 4) * 8;   // MFMA A/B fragment addressing

  f32x4 acc[4][4] = {};

  for (int k0 = 0; k0 < HID; k0 += 32) {
    const f16* gAh = Ah + (size_t)(m0 + srow) * HID + k0 + scol;
    const f16* gAl = Al + (size_t)(m0 + srow) * HID + k0 + scol;
    const f16* gBh = Bh + (size_t)(n0 + srow) * HID + k0 + scol;
    const f16* gBl = Bl + (size_t)(n0 + srow) * HID + k0 + scol;
    async_copy16(gAh,                    &sAh[srow * 32 + scol]);
    async_copy16(gAh + (size_t)64 * HID, &sAh[(srow + 64) * 32 + scol]);
    async_copy16(gAl,                    &sAl[srow * 32 + scol]);
    async_copy16(gAl + (size_t)64 * HID, &sAl[(srow + 64) * 32 + scol]);
    async_copy16(gBh,                    &sBh[srow * 32 + scol]);
    async_copy16(gBh + (size_t)64 * HID, &sBh[(srow + 64) * 32 + scol]);
    async_copy16(gBl,                    &sBl[srow * 32 + scol]);
    async_copy16(gBl + (size_t)64 * HID, &sBl[(srow + 64) * 32 + scol]);
    __syncthreads();
    f16x8 ah[4], al[4], bh[4], bl[4];
    #pragma unroll
    for (int i = 0; i < 4; ++i) {
      ah[i] = *(const f16x8*)&sAh[(wm + i * 16 + lm) * 32 + lk];
      al[i] = *(const f16x8*)&sAl[(wm + i * 16 + lm) * 32 + lk];
      bh[i] = *(const f16x8*)&sBh[(wn + i * 16 + lm) * 32 + lk];
      bl[i] = *(const f16x8*)&sBl[(wn + i * 16 + lm) * 32 + lk];
    }
    #pragma unroll
    for (int i = 0; i < 4; ++i) {
      #pragma unroll
      for (int j = 0; j < 4; ++j) {
        acc[i][j] = __builtin_amdgcn_mfma_f32_16x16x32_f16(ah[i], bh[j], acc[i][j], 0, 0, 0);
        acc[i][j] = __builtin_amdgcn_mfma_f32_16x16x32_f16(ah[i], bl[j], acc[i][j], 0, 0, 0);
        acc[i][j] = __builtin_amdgcn_mfma_f32_16x16x32_f16(al[i], bh[j], acc[i][j], 0, 0, 0);
      }
    }
    __syncthreads();
  }
  const int lq4 = (lane >> 4) * 4;
  #pragma unroll
  for (int i = 0; i < 4; ++i) {
    #pragma unroll
    for (int j = 0; j < 4; ++j) {
      int mG = m0 + wm + i * 16 + lq4;
      int nG = n0 + wn + j * 16 + lm;
      #pragma unroll
      for (int r = 0; r < 4; ++r)
        C[(size_t)(mG + r) * ldc + nG] = acc[i][j][r];
    }
  }
}

// ---------------- plain fp16 GEMM for logits: C[M,N] = scale * A[M,K] * B[N,K]^T ----------------
__global__ __launch_bounds__(256) void gemm_f16(
    const f16* __restrict__ A, const f16* __restrict__ B, float* __restrict__ C, int N) {
  __shared__ __align__(16) f16 sA[128 * 32], sB[128 * 32];
  const int m0 = blockIdx.x * 128, n0 = blockIdx.y * 128;
  const int t = threadIdx.x;
  const int lane = t & 63, wave = t >> 6;
  const int wm = (wave >> 1) * 64, wn = (wave & 1) * 64;
  const int srow = t >> 2, scol = (t & 3) * 8;
  const int lm = lane & 15, lk = (lane >> 4) * 8;

  f32x4 acc[4][4] = {};

  for (int k0 = 0; k0 < HID; k0 += 32) {
    const f16* gA = A + (size_t)(m0 + srow) * HID + k0 + scol;
    const f16* gB = B + (size_t)(n0 + srow) * HID + k0 + scol;
    async_copy16(gA,                    &sA[srow * 32 + scol]);
    async_copy16(gA + (size_t)64 * HID, &sA[(srow + 64) * 32 + scol]);
    async_copy16(gB,                    &sB[srow * 32 + scol]);
    async_copy16(gB + (size_t)64 * HID, &sB[(srow + 64) * 32 + scol]);
    __syncthreads();
    f16x8 af[4], bf[4];
    #pragma unroll
    for (int i = 0; i < 4; ++i) {
      af[i] = *(const f16x8*)&sA[(wm + i * 16 + lm) * 32 + lk];
      bf[i] = *(const f16x8*)&sB[(wn + i * 16 + lm) * 32 + lk];
    }
    #pragma unroll
    for (int i = 0; i < 4; ++i)
      #pragma unroll
      for (int j = 0; j < 4; ++j)
        acc[i][j] = __builtin_amdgcn_mfma_f32_16x16x32_f16(af[i], bf[j], acc[i][j], 0, 0, 0);
    __syncthreads();
  }
  const int lq4 = (lane >> 4) * 4;
  #pragma unroll
  for (int i = 0; i < 4; ++i) {
    #pragma unroll
    for (int j = 0; j < 4; ++j) {
      int mG = m0 + wm + i * 16 + lq4;
      int nG = n0 + wn + j * 16 + lm;
      #pragma unroll
      for (int r = 0; r < 4; ++r)
        C[(size_t)(mG + r) * N + nG] = acc[i][j][r] * FINAL_SCALE;
    }
  }
}

// ---------------- cos_sim -> bp / sel / mask (replicates reference fp32 rounding) ----------------
__global__ void cos_bp_kernel(const float* __restrict__ QK, float* __restrict__ bp,
                              float* __restrict__ sel, int* __restrict__ msk) {
  int t = blockIdx.x;  // 0..4094 -> produces bp[t+1]
  const float* q = QK + (size_t)t * 4096;             // Q[t]
  const float* k = QK + (size_t)(t + 1) * 4096 + HID; // K[t+1]
  float d = 0.f, q2 = 0.f, k2 = 0.f;
  #pragma unroll
  for (int s = 0; s < 8; ++s) {
    int j = threadIdx.x + s * 256;
    float qv = q[j], kv = k[j];
    d = fmaf(qv, kv, d); q2 = fmaf(qv, qv, q2); k2 = fmaf(kv, kv, k2);
  }
  #pragma unroll
  for (int off = 32; off > 0; off >>= 1) {
    d += __shfl_down(d, off); q2 += __shfl_down(q2, off); k2 += __shfl_down(k2, off);
  }
  __shared__ float rd[4], rq[4], rk[4];
  int wave = threadIdx.x >> 6;
  if ((threadIdx.x & 63) == 0) { rd[wave] = d; rq[wave] = q2; rk[wave] = k2; }
  __syncthreads();
  if (threadIdx.x == 0) {
    d  = rd[0] + rd[1] + rd[2] + rd[3];
    q2 = rq[0] + rq[1] + rq[2] + rq[3];
    k2 = rk[0] + rk[1] + rk[2] + rk[3];
    float nq = fmaxf(sqrtf(q2), 1e-12f), nk = fmaxf(sqrtf(k2), 1e-12f);
    float c = d / (nq * nk);
    float b = fminf(fmaxf((1.0f - c) * 0.5f, 0.0f), 1.0f);
    int m = (b >= 0.5f) ? 1 : 0;   // reference semantics: test on rounded bp, not on cos
    bp[t + 1] = b; msk[t + 1] = m; sel[t + 1] = m ? b : 1.0f - b;
    if (t == 0) { bp[0] = 1.0f; msk[0] = 1; sel[0] = 1.0f; }  // PAD_PROB=1 at t=0
  }
}

// ---------------- aux loss ----------------
__global__ void aux_kernel(const float* __restrict__ bp, const int* __restrict__ msk,
                           float* __restrict__ auxout) {
  float s1 = 0.f, s2 = 0.f;
  for (int i = threadIdx.x; i < SEQ; i += 256) { s1 += bp[i]; s2 += (float)msk[i]; }
  #pragma unroll
  for (int off = 32; off > 0; off >>= 1) { s1 += __shfl_down(s1, off); s2 += __shfl_down(s2, off); }
  __shared__ float r1[4], r2[4];
  int wave = threadIdx.x >> 6;
  if ((threadIdx.x & 63) == 0) { r1[wave] = s1; r2[wave] = s2; }
  __syncthreads();
  if (threadIdx.x == 0) {
    float G = (r1[0] + r1[1] + r1[2] + r1[3]) * (1.0f / SEQ);
    float F = (r2[0] + r2[1] + r2[2] + r2[3]) * (1.0f / SEQ);
    auxout[0] = 2.0f * (F * G + (1.0f - F) * (1.0f - G));  // R=2
  }
}

// ---------------- chunked EMA scan: pass 1 (per-chunk local B + scalar A) ----------------
__global__ void scan_pass1(const float* __restrict__ h, const float* __restrict__ sel,
                           const int* __restrict__ msk, float* __restrict__ Bc,
                           float* __restrict__ Ac) {
  int c = blockIdx.x;
  float s[8] = {0, 0, 0, 0, 0, 0, 0, 0};
  float ap = 1.0f;
  int t0 = c * CHUNK;
  for (int t = t0; t < t0 + CHUNK; ++t) {
    if (msk[t]) {                        // block-uniform branch
      float p = sel[t];
      float om = 1.0f - p;
      ap *= om;
      #pragma unroll
      for (int u = 0; u < 8; ++u) {
        int dim = threadIdx.x + u * 256;
        float x = h[(size_t)t * HID + dim] * CPT_SCALE;
        s[u] = s[u] * om + x * p;
      }
    }
  }
  #pragma unroll
  for (int u = 0; u < 8; ++u) Bc[c * HID + threadIdx.x + u * 256] = s[u];
  if (threadIdx.x == 0) Ac[c] = ap;
}

// ---------------- pass 2: chunk-level scan (64 steps) ----------------
__global__ void scan_pass2(const float* __restrict__ Bc, const float* __restrict__ Ac,
                           float* __restrict__ Sin) {
  int dim = blockIdx.x * 256 + threadIdx.x;  // grid = 8 blocks
  float s = 0.f;
  for (int c = 0; c < NCHUNK; ++c) {
    Sin[c * HID + dim] = s;                  // incoming state of chunk c
    s = Ac[c] * s + Bc[c * HID + dim];
  }
}

// ---------------- pass 3: replay + fused epilogue -> fp16 h_out (scaled) ----------------
__global__ void scan_pass3(const float* __restrict__ h, const float* __restrict__ sel,
                           const int* __restrict__ msk, const float* __restrict__ Sin,
                           f16* __restrict__ hout) {
  int c = blockIdx.x;
  float s[8];
  #pragma unroll
  for (int u = 0; u < 8; ++u) s[u] = Sin[c * HID + threadIdx.x + u * 256];
  int t0 = c * CHUNK;
  for (int t = t0; t < t0 + CHUNK; ++t) {
    int m = msk[t];
    float p = sel[t];
    float om = 1.0f - p;
    #pragma unroll
    for (int u = 0; u < 8; ++u) {
      int dim = threadIdx.x + u * 256;
      float hv = h[(size_t)t * HID + dim];
      if (m) s[u] = s[u] * om + (hv * CPT_SCALE) * p;
      hout[(size_t)t * HID + dim] = (f16)((hv + s[u]) * OUT_SCALE);
    }
  }
}

extern "C" void kernel_launch(void* const* d_in, const int* in_sizes, int n_in,
                              void* d_out, int out_size, void* d_ws, size_t ws_size,
                              hipStream_t stream) {
  const int*   ids = (const int*)d_in[0];
  const float* emb = (const float*)d_in[1];
  const float* qw  = (const float*)d_in[2];
  const float* kw  = (const float*)d_in[3];
  const float* lmw = (const float*)d_in[4];
  float* out = (float*)d_out;

  // Scratch in d_out (524 MB): all dead before the final GEMM overwrites it with logits.
  char* ob = (char*)d_out;
  float* QK  = (float*)(ob + 0);           // 4096x4096 f32 (Q | K)   67,108,864 B
  float* h   = (float*)(ob + 67108864);    // 4096x2048 f32           33,554,432 B
  f16*  hhi  = (f16*)  (ob + 100663296);   // 16,777,216 B
  f16*  hlo  = (f16*)  (ob + 117440512);   // 16,777,216 B
  f16*  whi  = (f16*)  (ob + 134217728);   // 4096x2048 f16 (qw;kw)   16,777,216 B
  f16*  wlo  = (f16*)  (ob + 150994944);   // 16,777,216 B
  float* bp  = (float*)(ob + 167772160);   // 4096 f32
  float* sel = (float*)(ob + 167788544);   // 4096 f32
  int*   msk = (int*)  (ob + 167804928);   // 4096 i32
  float* Ac  = (float*)(ob + 167821312);   // 64 f32
  float* Bc  = (float*)(ob + 167837696);   // 64x2048 f32  524,288 B
  float* Sin = (float*)(ob + 168361984);   // 64x2048 f32  524,288 B
  // d_ws: only buffers that must survive into the final GEMM (148 MB).
  char* wb = (char*)d_ws;
  f16* hout = (f16*)(wb + 0);              // 4096x2048 f16  16,777,216 B
  f16* lm16 = (f16*)(wb + 16777216);       // 32000x2048 f16 131,072,000 B

  gather_split<<<SEQ, 256, 0, stream>>>(ids, emb, h, hhi, hlo);
  split_w<<<4096, 256, 0, stream>>>(qw, whi, wlo);
  split_w<<<4096, 256, 0, stream>>>(kw, whi + (size_t)HID * HID, wlo + (size_t)HID * HID);
  gemm_split3<<<dim3(32, 32), 256, 0, stream>>>(hhi, hlo, whi, wlo, QK, 4096);
  cos_bp_kernel<<<SEQ - 1, 256, 0, stream>>>(QK, bp, sel, msk);
  aux_kernel<<<1, 256, 0, stream>>>(bp, msk, out + (size_t)SEQ * NVOCAB);
  scan_pass1<<<NCHUNK, 256, 0, stream>>>(h, sel, msk, Bc, Ac);
  scan_pass2<<<8, 256, 0, stream>>>(Bc, Ac, Sin);
  scan_pass3<<<NCHUNK, 256, 0, stream>>>(h, sel, msk, Sin, hout);
  conv_lm<<<64000, 256, 0, stream>>>(lmw, lm16);
  gemm_f16<<<dim3(32, 250), 256, 0, stream>>>(hout, lm16, out, NVOCAB);
}